// Round 1
// baseline (732.265 us; speedup 1.0000x reference)
//
#include <hip/hip_runtime.h>
#include <math.h>

#define HDIM 256
#define FDIM 768

// ---------------- CSR build ----------------

__global__ void k_hist(const int* __restrict__ dst, int* __restrict__ cnt, int E) {
  int e = blockIdx.x * 256 + threadIdx.x;
  if (e < E) atomicAdd(&cnt[dst[e]], 1);
}

__global__ void k_scan1(const int* __restrict__ cnt, int* __restrict__ offsets,
                        int* __restrict__ bsums, int n) {
  __shared__ int s[256];
  int i = blockIdx.x * 256 + threadIdx.x;
  int v = (i < n) ? cnt[i] : 0;
  s[threadIdx.x] = v;
  __syncthreads();
  for (int off = 1; off < 256; off <<= 1) {
    int t = (threadIdx.x >= off) ? s[threadIdx.x - off] : 0;
    __syncthreads();
    s[threadIdx.x] += t;
    __syncthreads();
  }
  if (i < n) offsets[i + 1] = s[threadIdx.x];
  if (blockIdx.x == 0 && threadIdx.x == 0) offsets[0] = 0;
  if (threadIdx.x == 255) bsums[blockIdx.x] = s[255];
}

__global__ void k_scan2(int* __restrict__ bsums, int nb) {
  __shared__ int s[256];
  int v = (threadIdx.x < nb) ? bsums[threadIdx.x] : 0;
  s[threadIdx.x] = v;
  __syncthreads();
  for (int off = 1; off < 256; off <<= 1) {
    int t = (threadIdx.x >= off) ? s[threadIdx.x - off] : 0;
    __syncthreads();
    s[threadIdx.x] += t;
    __syncthreads();
  }
  if (threadIdx.x < nb) bsums[threadIdx.x] = s[threadIdx.x] - v;  // exclusive
}

__global__ void k_scan3(int* __restrict__ offsets, const int* __restrict__ bsums, int n) {
  int i = blockIdx.x * 256 + threadIdx.x;
  if (i < n) offsets[i + 1] += bsums[blockIdx.x];
}

__global__ void k_scatter(const int* __restrict__ dst, int* __restrict__ cursor,
                          int* __restrict__ elist, int E) {
  int e = blockIdx.x * 256 + threadIdx.x;
  if (e < E) {
    int p = atomicAdd(&cursor[dst[e]], 1);
    elist[p] = e;
  }
}

// ---------------- edge-attention precompute ----------------

// v1 = We1 @ ae1, v2 = We2 @ ae2   (each [768])
__global__ void k_compute_v(const float* __restrict__ We1, const float* __restrict__ ae1,
                            const float* __restrict__ We2, const float* __restrict__ ae2,
                            float* __restrict__ v1, float* __restrict__ v2) {
  int row = blockIdx.x * 4 + (threadIdx.x >> 6);
  if (row >= 2 * FDIM) return;
  int lane = threadIdx.x & 63;
  const float* W = (row < FDIM) ? We1 : We2;
  const float* a = (row < FDIM) ? ae1 : ae2;
  int r = (row < FDIM) ? row : row - FDIM;
  float4 w = *(const float4*)&W[(size_t)r * HDIM + lane * 4];
  float4 av = *(const float4*)&a[lane * 4];
  float p = w.x * av.x + w.y * av.y + w.z * av.z + w.w * av.w;
  #pragma unroll
  for (int off = 32; off; off >>= 1) p += __shfl_down(p, off, 64);
  if (lane == 0) ((row < FDIM) ? v1 : v2)[r] = p;
}

// alpha_e1[e] = edge_attr[e]·v1 ; alpha_e2[e] = edge_attr[e]·v2  (single pass over edge_attr)
__global__ __launch_bounds__(256) void k_edge_alpha(const float* __restrict__ ea,
                                                    const float* __restrict__ v1,
                                                    const float* __restrict__ v2,
                                                    float* __restrict__ o1,
                                                    float* __restrict__ o2, int E) {
  __shared__ float sv1[FDIM], sv2[FDIM];
  for (int i = threadIdx.x; i < FDIM; i += 256) { sv1[i] = v1[i]; sv2[i] = v2[i]; }
  __syncthreads();
  int e = blockIdx.x * 4 + (threadIdx.x >> 6);
  if (e >= E) return;
  int lane = threadIdx.x & 63;
  const float* row = ea + (size_t)e * FDIM;
  float p1 = 0.f, p2 = 0.f;
  #pragma unroll
  for (int t = 0; t < 3; ++t) {
    int idx = t * 256 + lane * 4;
    float4 x = *(const float4*)&row[idx];
    float4 a = *(const float4*)&sv1[idx];
    float4 b = *(const float4*)&sv2[idx];
    p1 += x.x * a.x + x.y * a.y + x.z * a.z + x.w * a.w;
    p2 += x.x * b.x + x.y * b.y + x.z * b.z + x.w * b.w;
  }
  #pragma unroll
  for (int off = 32; off; off >>= 1) {
    p1 += __shfl_down(p1, off, 64);
    p2 += __shfl_down(p2, off, 64);
  }
  if (lane == 0) { o1[e] = p1; o2[e] = p2; }
}

// ---------------- fp32 GEMM, C[M][256] = A[M][K] @ B[K][256], fused row-dots ----------------
// BM=32, BN=256 (full width), BK=16; 256 threads; each thread: 8 rows x 4 cols.
// Epilogue: sOut[r] = C[r]·a_src, dOut[r] = C[r]·a_dst (wave reduction, full row in one wave).

__global__ __launch_bounds__(256) void k_sgemm(const float* __restrict__ A,
                                               const float* __restrict__ B,
                                               float* __restrict__ C,
                                               float* __restrict__ sOut,
                                               float* __restrict__ dOut,
                                               const float* __restrict__ a_src,
                                               const float* __restrict__ a_dst,
                                               int M, int K) {
  __shared__ float As[16][36];    // transposed: As[k][m]
  __shared__ float Bs[16][260];
  int t = threadIdx.x;
  int bm = blockIdx.x * 32;
  int tx = t & 63;   // column group: cols tx*4..tx*4+3
  int ty = t >> 6;   // wave id: rows ty*8..ty*8+7
  float acc[8][4] = {};
  for (int k0 = 0; k0 < K; k0 += 16) {
    if (t < 128) {
      int ar = t >> 2;          // 0..31
      int ak = (t & 3) * 4;     // 0,4,8,12
      float4 av = make_float4(0.f, 0.f, 0.f, 0.f);
      if (bm + ar < M) av = *(const float4*)&A[(size_t)(bm + ar) * K + k0 + ak];
      As[ak + 0][ar] = av.x; As[ak + 1][ar] = av.y;
      As[ak + 2][ar] = av.z; As[ak + 3][ar] = av.w;
    }
    #pragma unroll
    for (int q = 0; q < 4; ++q) {
      int f = q * 256 + t;           // 0..1023 float4 slots of 16x256 tile
      int br = f >> 6;
      int bc = (f & 63) * 4;
      *(float4*)&Bs[br][bc] = *(const float4*)&B[(size_t)(k0 + br) * HDIM + bc];
    }
    __syncthreads();
    #pragma unroll
    for (int kk = 0; kk < 16; ++kk) {
      float4 b = *(float4*)&Bs[kk][tx * 4];
      float4 a0 = *(float4*)&As[kk][ty * 8];
      float4 a1 = *(float4*)&As[kk][ty * 8 + 4];
      acc[0][0] += a0.x * b.x; acc[0][1] += a0.x * b.y; acc[0][2] += a0.x * b.z; acc[0][3] += a0.x * b.w;
      acc[1][0] += a0.y * b.x; acc[1][1] += a0.y * b.y; acc[1][2] += a0.y * b.z; acc[1][3] += a0.y * b.w;
      acc[2][0] += a0.z * b.x; acc[2][1] += a0.z * b.y; acc[2][2] += a0.z * b.z; acc[2][3] += a0.z * b.w;
      acc[3][0] += a0.w * b.x; acc[3][1] += a0.w * b.y; acc[3][2] += a0.w * b.z; acc[3][3] += a0.w * b.w;
      acc[4][0] += a1.x * b.x; acc[4][1] += a1.x * b.y; acc[4][2] += a1.x * b.z; acc[4][3] += a1.x * b.w;
      acc[5][0] += a1.y * b.x; acc[5][1] += a1.y * b.y; acc[5][2] += a1.y * b.z; acc[5][3] += a1.y * b.w;
      acc[6][0] += a1.z * b.x; acc[6][1] += a1.z * b.y; acc[6][2] += a1.z * b.z; acc[6][3] += a1.z * b.w;
      acc[7][0] += a1.w * b.x; acc[7][1] += a1.w * b.y; acc[7][2] += a1.w * b.z; acc[7][3] += a1.w * b.w;
    }
    __syncthreads();
  }
  float4 asv = *(const float4*)&a_src[tx * 4];
  float4 adv = *(const float4*)&a_dst[tx * 4];
  #pragma unroll
  for (int i = 0; i < 8; ++i) {
    int r = bm + ty * 8 + i;
    bool live = (r < M);
    if (live)
      *(float4*)&C[(size_t)r * HDIM + tx * 4] =
          make_float4(acc[i][0], acc[i][1], acc[i][2], acc[i][3]);
    float ps = acc[i][0] * asv.x + acc[i][1] * asv.y + acc[i][2] * asv.z + acc[i][3] * asv.w;
    float pd = acc[i][0] * adv.x + acc[i][1] * adv.y + acc[i][2] * adv.z + acc[i][3] * adv.w;
    #pragma unroll
    for (int off = 32; off; off >>= 1) {
      ps += __shfl_down(ps, off, 64);
      pd += __shfl_down(pd, off, 64);
    }
    if (tx == 0 && live) { sOut[r] = ps; dOut[r] = pd; }
  }
}

// ---------------- attention logits ----------------

__global__ void k_alpha_combine(const float* __restrict__ s, const float* __restrict__ d,
                                const float* __restrict__ ae, const int* __restrict__ src,
                                const int* __restrict__ dst, float* __restrict__ alpha, int E) {
  int e = blockIdx.x * 256 + threadIdx.x;
  if (e < E) {
    float a = s[src[e]] + d[dst[e]] + ae[e];
    alpha[e] = (a > 0.f) ? a : 0.2f * a;  // leaky_relu(0.2)
  }
}

// ---------------- per-node softmax + aggregation (wave per node) ----------------

__global__ __launch_bounds__(256) void k_aggregate(const float* __restrict__ xl,
                                                   const float* __restrict__ alpha,
                                                   const int* __restrict__ src,
                                                   const int* __restrict__ offsets,
                                                   const int* __restrict__ elist,
                                                   const float* __restrict__ bias,
                                                   float* __restrict__ out, int n, int doRelu) {
  int node = blockIdx.x * 4 + (threadIdx.x >> 6);
  if (node >= n) return;
  int lane = threadIdx.x & 63;
  int beg = offsets[node], end = offsets[node + 1];
  float acc0 = 0.f, acc1 = 0.f, acc2 = 0.f, acc3 = 0.f;
  if (end > beg) {
    float m = -1e30f;
    for (int j = beg; j < end; ++j) m = fmaxf(m, alpha[elist[j]]);
    float den = 0.f;
    for (int j = beg; j < end; ++j) den += expf(alpha[elist[j]] - m);
    float inv = 1.f / den;
    for (int j = beg; j < end; ++j) {
      int e = elist[j];
      float wgt = expf(alpha[e] - m) * inv;
      const float* row = xl + (size_t)src[e] * HDIM;
      acc0 += wgt * row[lane];
      acc1 += wgt * row[lane + 64];
      acc2 += wgt * row[lane + 128];
      acc3 += wgt * row[lane + 192];
    }
  }
  float o0 = acc0 + bias[lane];
  float o1 = acc1 + bias[lane + 64];
  float o2 = acc2 + bias[lane + 128];
  float o3 = acc3 + bias[lane + 192];
  if (doRelu) {
    o0 = fmaxf(o0, 0.f); o1 = fmaxf(o1, 0.f);
    o2 = fmaxf(o2, 0.f); o3 = fmaxf(o3, 0.f);
  }
  float* orow = out + (size_t)node * HDIM;
  orow[lane] = o0; orow[lane + 64] = o1; orow[lane + 128] = o2; orow[lane + 192] = o3;
}

// ---------------- prediction head ----------------

__global__ void k_head(const float* __restrict__ titles, const int* __restrict__ nodes,
                       const float* __restrict__ Wp, const float* __restrict__ bp,
                       float* __restrict__ out, int Bn) {
  int b = blockIdx.x * 4 + (threadIdx.x >> 6);
  if (b >= Bn) return;
  int lane = threadIdx.x & 63;
  const float* r0 = titles + (size_t)nodes[b] * HDIM;
  const float* r1 = titles + (size_t)nodes[Bn + b] * HDIM;
  float s0 = 0.f, s1 = 0.f, s2 = 0.f;
  #pragma unroll
  for (int i = 0; i < 4; ++i) {
    int h = lane + 64 * i;
    float c = r0[h] * r1[h];
    s0 += c * Wp[h * 3 + 0];
    s1 += c * Wp[h * 3 + 1];
    s2 += c * Wp[h * 3 + 2];
  }
  #pragma unroll
  for (int off = 32; off; off >>= 1) {
    s0 += __shfl_down(s0, off, 64);
    s1 += __shfl_down(s1, off, 64);
    s2 += __shfl_down(s2, off, 64);
  }
  if (lane == 0) {
    out[b * 3 + 0] = s0 + bp[0];
    out[b * 3 + 1] = s1 + bp[1];
    out[b * 3 + 2] = s2 + bp[2];
  }
}

// ---------------- launch ----------------

extern "C" void kernel_launch(void* const* d_in, const int* in_sizes, int n_in,
                              void* d_out, int out_size, void* d_ws, size_t ws_size,
                              hipStream_t stream) {
  const float* x         = (const float*)d_in[0];
  const float* edge_attr = (const float*)d_in[1];
  const float* W1  = (const float*)d_in[2];
  const float* as1 = (const float*)d_in[3];
  const float* ad1 = (const float*)d_in[4];
  const float* We1 = (const float*)d_in[5];
  const float* ae1 = (const float*)d_in[6];
  const float* b1  = (const float*)d_in[7];
  const float* W2  = (const float*)d_in[8];
  const float* as2 = (const float*)d_in[9];
  const float* ad2 = (const float*)d_in[10];
  const float* We2 = (const float*)d_in[11];
  const float* ae2 = (const float*)d_in[12];
  const float* b2  = (const float*)d_in[13];
  const float* Wp  = (const float*)d_in[14];
  const float* bp  = (const float*)d_in[15];
  const int* edge_index = (const int*)d_in[16];
  const int* nodes      = (const int*)d_in[17];

  const int N  = in_sizes[0] / FDIM;
  const int E  = in_sizes[16] / 2;
  const int Bn = in_sizes[17] / 2;
  const int* srcArr = edge_index;
  const int* dstArr = edge_index + E;

  // workspace carving (256B aligned)
  char* w = (char*)d_ws;
  auto carve = [&](size_t bytes) -> void* {
    void* p = (void*)w;
    w += (bytes + 255) & ~(size_t)255;
    return p;
  };
  float* P0 = (float*)carve(sizeof(float) * (size_t)N * HDIM);  // xl1, later titles
  float* P1 = (float*)carve(sizeof(float) * (size_t)N * HDIM);  // h
  float* P2 = (float*)carve(sizeof(float) * (size_t)N * HDIM);  // xl2
  float* ae1Arr = (float*)carve(sizeof(float) * E);
  float* ae2Arr = (float*)carve(sizeof(float) * E);
  float* alphaE = (float*)carve(sizeof(float) * E);
  float* sArr = (float*)carve(sizeof(float) * N);
  float* dArr = (float*)carve(sizeof(float) * N);
  float* v1 = (float*)carve(sizeof(float) * FDIM);
  float* v2 = (float*)carve(sizeof(float) * FDIM);
  int* cnt     = (int*)carve(sizeof(int) * N);
  int* offsets = (int*)carve(sizeof(int) * (N + 1));
  int* cursor  = (int*)carve(sizeof(int) * N);
  int* elist   = (int*)carve(sizeof(int) * E);
  int* bsums   = (int*)carve(sizeof(int) * 256);

  const int nbScan = (N + 255) / 256;

  // CSR build (dst-indexed)
  hipMemsetAsync(cnt, 0, sizeof(int) * N, stream);
  k_hist<<<(E + 255) / 256, 256, 0, stream>>>(dstArr, cnt, E);
  k_scan1<<<nbScan, 256, 0, stream>>>(cnt, offsets, bsums, N);
  k_scan2<<<1, 256, 0, stream>>>(bsums, nbScan);
  k_scan3<<<nbScan, 256, 0, stream>>>(offsets, bsums, N);
  hipMemcpyAsync(cursor, offsets, sizeof(int) * N, hipMemcpyDeviceToDevice, stream);
  k_scatter<<<(E + 255) / 256, 256, 0, stream>>>(dstArr, cursor, elist, E);

  // edge attention terms (one pass over edge_attr for both layers)
  k_compute_v<<<(2 * FDIM) / 4, 256, 0, stream>>>(We1, ae1, We2, ae2, v1, v2);
  k_edge_alpha<<<(E + 3) / 4, 256, 0, stream>>>(edge_attr, v1, v2, ae1Arr, ae2Arr, E);

  // ----- layer 1 -----
  k_sgemm<<<(N + 31) / 32, 256, 0, stream>>>(x, W1, P0, sArr, dArr, as1, ad1, N, FDIM);
  k_alpha_combine<<<(E + 255) / 256, 256, 0, stream>>>(sArr, dArr, ae1Arr, srcArr, dstArr, alphaE, E);
  k_aggregate<<<(N + 3) / 4, 256, 0, stream>>>(P0, alphaE, srcArr, offsets, elist, b1, P1, N, 1);

  // ----- layer 2 -----
  k_sgemm<<<(N + 31) / 32, 256, 0, stream>>>(P1, W2, P2, sArr, dArr, as2, ad2, N, HDIM);
  k_alpha_combine<<<(E + 255) / 256, 256, 0, stream>>>(sArr, dArr, ae2Arr, srcArr, dstArr, alphaE, E);
  k_aggregate<<<(N + 3) / 4, 256, 0, stream>>>(P2, alphaE, srcArr, offsets, elist, b2, P0, N, 0);

  // ----- head -----
  k_head<<<(Bn + 3) / 4, 256, 0, stream>>>(P0, nodes, Wp, bp, (float*)d_out, Bn);
}

// Round 3
// 426.707 us; speedup vs baseline: 1.7161x; 1.7161x over previous
//
#include <hip/hip_runtime.h>
#include <math.h>

#define HDIM 256
#define FDIM 768
#define BM 128
#define BK 32

typedef __attribute__((ext_vector_type(8))) short short8;
typedef __attribute__((ext_vector_type(4))) float f32x4;
typedef __attribute__((ext_vector_type(4))) unsigned short us4;

__device__ __forceinline__ unsigned short f2bf(float f) {
  unsigned int u = __float_as_uint(f);
  unsigned int r = (u + 0x7FFFu + ((u >> 16) & 1u)) >> 16;
  return (unsigned short)r;
}
__device__ __forceinline__ float bf2f(unsigned short b) {
  return __uint_as_float(((unsigned int)b) << 16);
}

__device__ __forceinline__ void gload_lds16(const void* g, void* l) {
  __builtin_amdgcn_global_load_lds(
      (const __attribute__((address_space(1))) void*)g,
      (__attribute__((address_space(3))) void*)l, 16, 0, 0);
}

// ---------------- CSR build ----------------

__global__ void k_hist(const int* __restrict__ dst, int* __restrict__ cnt, int E) {
  int e = blockIdx.x * 256 + threadIdx.x;
  if (e < E) atomicAdd(&cnt[dst[e]], 1);
}

__global__ void k_scan1(const int* __restrict__ cnt, int* __restrict__ offsets,
                        int* __restrict__ bsums, int n) {
  __shared__ int s[256];
  int i = blockIdx.x * 256 + threadIdx.x;
  int v = (i < n) ? cnt[i] : 0;
  s[threadIdx.x] = v;
  __syncthreads();
  for (int off = 1; off < 256; off <<= 1) {
    int t = (threadIdx.x >= off) ? s[threadIdx.x - off] : 0;
    __syncthreads();
    s[threadIdx.x] += t;
    __syncthreads();
  }
  if (i < n) offsets[i + 1] = s[threadIdx.x];
  if (blockIdx.x == 0 && threadIdx.x == 0) offsets[0] = 0;
  if (threadIdx.x == 255) bsums[blockIdx.x] = s[255];
}

__global__ void k_scan2(int* __restrict__ bsums, int nb) {
  __shared__ int s[256];
  int v = (threadIdx.x < nb) ? bsums[threadIdx.x] : 0;
  s[threadIdx.x] = v;
  __syncthreads();
  for (int off = 1; off < 256; off <<= 1) {
    int t = (threadIdx.x >= off) ? s[threadIdx.x - off] : 0;
    __syncthreads();
    s[threadIdx.x] += t;
    __syncthreads();
  }
  if (threadIdx.x < nb) bsums[threadIdx.x] = s[threadIdx.x] - v;  // exclusive
}

__global__ void k_scan3(int* __restrict__ offsets, const int* __restrict__ bsums, int n) {
  int i = blockIdx.x * 256 + threadIdx.x;
  if (i < n) offsets[i + 1] += bsums[blockIdx.x];
}

__global__ void k_scatter(const int* __restrict__ dst, int* __restrict__ cursor,
                          int* __restrict__ elist, int E) {
  int e = blockIdx.x * 256 + threadIdx.x;
  if (e < E) {
    int p = atomicAdd(&cursor[dst[e]], 1);
    elist[p] = e;
  }
}

// ---------------- edge-attention precompute ----------------

__global__ void k_compute_v(const float* __restrict__ We1, const float* __restrict__ ae1,
                            const float* __restrict__ We2, const float* __restrict__ ae2,
                            float* __restrict__ v1, float* __restrict__ v2) {
  int row = blockIdx.x * 4 + (threadIdx.x >> 6);
  if (row >= 2 * FDIM) return;
  int lane = threadIdx.x & 63;
  const float* W = (row < FDIM) ? We1 : We2;
  const float* a = (row < FDIM) ? ae1 : ae2;
  int r = (row < FDIM) ? row : row - FDIM;
  float4 w = *(const float4*)&W[(size_t)r * HDIM + lane * 4];
  float4 av = *(const float4*)&a[lane * 4];
  float p = w.x * av.x + w.y * av.y + w.z * av.z + w.w * av.w;
  #pragma unroll
  for (int off = 32; off; off >>= 1) p += __shfl_down(p, off, 64);
  if (lane == 0) ((row < FDIM) ? v1 : v2)[r] = p;
}

__global__ __launch_bounds__(256) void k_edge_alpha(const float* __restrict__ ea,
                                                    const float* __restrict__ v1,
                                                    const float* __restrict__ v2,
                                                    float* __restrict__ o1,
                                                    float* __restrict__ o2, int E) {
  __shared__ float sv1[FDIM], sv2[FDIM];
  for (int i = threadIdx.x; i < FDIM; i += 256) { sv1[i] = v1[i]; sv2[i] = v2[i]; }
  __syncthreads();
  int e = blockIdx.x * 4 + (threadIdx.x >> 6);
  if (e >= E) return;
  int lane = threadIdx.x & 63;
  const float* row = ea + (size_t)e * FDIM;
  float p1 = 0.f, p2 = 0.f;
  #pragma unroll
  for (int t = 0; t < 3; ++t) {
    int idx = t * 256 + lane * 4;
    float4 x = *(const float4*)&row[idx];
    float4 a = *(const float4*)&sv1[idx];
    float4 b = *(const float4*)&sv2[idx];
    p1 += x.x * a.x + x.y * a.y + x.z * a.z + x.w * a.w;
    p2 += x.x * b.x + x.y * b.y + x.z * b.z + x.w * b.w;
  }
  #pragma unroll
  for (int off = 32; off; off >>= 1) {
    p1 += __shfl_down(p1, off, 64);
    p2 += __shfl_down(p2, off, 64);
  }
  if (lane == 0) { o1[e] = p1; o2[e] = p2; }
}

// ---------------- weight transpose+convert: W [K][H] f32 -> Wt [H][K] bf16 ----------------

__global__ void k_cvtW(const float* __restrict__ W, unsigned short* __restrict__ Wt, int K) {
  int n = blockIdx.x;  // 0..HDIM-1
  for (int k = threadIdx.x; k < K; k += 256)
    Wt[(size_t)n * K + k] = f2bf(W[(size_t)k * HDIM + n]);
}

// ---------------- bf16 MFMA GEMM: C[M][HDIM] (f32) = A[M][K] @ Bt[HDIM][K]^T ----------------
// BM=128, BN=256(full), BK=32. 512 threads = 8 waves (2m x 4n), wave tile 64x64.
// LDS physical layout is CHUNK-MAJOR (chunk = 8 contiguous k = 16B):
//   As: p = c*2048 + m*16   (c=0..3, m=0..127)   -> 8KB
//   Bs: p = c*4096 + n*16   (c=0..3, n=0..255)   -> 16KB
// Fragment read (lane l, row base+(l&15), chunk l>>4) is 16 consecutive 16B slots
// per quarter-wave -> conflict-minimal, no swizzle needed. gload_lds dest stays
// linear (t*16); the permutation is realized via the per-lane GLOBAL src address.

template <bool AF32>
__global__ __launch_bounds__(512) void k_gemm(const void* __restrict__ Ain,
                                              const unsigned short* __restrict__ Bt,
                                              float* __restrict__ C,
                                              int M, int K) {
  __shared__ unsigned char lds[8192 + 16384];
  unsigned char* As = lds;
  unsigned char* Bs = lds + 8192;
  const int t = threadIdx.x;
  const int l = t & 63;
  const int w = t >> 6;
  const int wm = w >> 2, wn = w & 3;
  const int bm = blockIdx.x * BM;

  f32x4 acc[4][4] = {};

  // A staging decode (bf16 path): dest s=t*16 -> chunk = t>>7, m = t&127
  int rowA = bm + (t & 127);
  if (rowA >= M) rowA = M - 1;
  const int cA = t >> 7;

  // A reg-staging (fp32 path): m = t>>2, kb = t&3 -> p = kb*2048 + m*16
  int rowAr = bm + (t >> 2);
  if (rowAr >= M) rowAr = M - 1;
  const int kbAr = t & 3;
  const int sAr = kbAr * 2048 + (t >> 2) * 16;

  // B staging decode: first 8KB: c = t>>8, n = t&255 ; second 8KB: c = 2+(t>>8)
  const int nB = t & 255;
  const int cB0 = t >> 8;
  const int cB1 = 2 + (t >> 8);

  // fragment read addresses
  int aAddr[4], bAddr[4];
  #pragma unroll
  for (int mt = 0; mt < 4; ++mt) {
    int m = wm * 64 + mt * 16 + (l & 15);
    aAddr[mt] = (l >> 4) * 2048 + m * 16;
  }
  #pragma unroll
  for (int nt = 0; nt < 4; ++nt) {
    int nn = wn * 64 + nt * 16 + (l & 15);
    bAddr[nt] = (l >> 4) * 4096 + nn * 16;
  }

  const int nsteps = K / BK;
  for (int ks = 0; ks < nsteps; ++ks) {
    const int k0 = ks * BK;
    __syncthreads();  // prev-iter LDS readers done
    if (AF32) {
      const float* A = (const float*)Ain;
      const float* p = A + (size_t)rowAr * K + k0 + kbAr * 8;
      float4 f0 = *(const float4*)p;
      float4 f1 = *(const float4*)(p + 4);
      short8 hv;
      hv[0] = (short)f2bf(f0.x); hv[1] = (short)f2bf(f0.y);
      hv[2] = (short)f2bf(f0.z); hv[3] = (short)f2bf(f0.w);
      hv[4] = (short)f2bf(f1.x); hv[5] = (short)f2bf(f1.y);
      hv[6] = (short)f2bf(f1.z); hv[7] = (short)f2bf(f1.w);
      *(short8*)(As + sAr) = hv;
    } else {
      const unsigned short* A = (const unsigned short*)Ain;
      gload_lds16(A + (size_t)rowA * K + k0 + cA * 8, As + t * 16);
    }
    gload_lds16(Bt + (size_t)nB * K + k0 + cB0 * 8, Bs + t * 16);
    gload_lds16(Bt + (size_t)nB * K + k0 + cB1 * 8, Bs + 8192 + t * 16);
    __syncthreads();  // barrier drains vmcnt+lgkmcnt

    short8 af[4], bfr[4];
    #pragma unroll
    for (int mt = 0; mt < 4; ++mt) af[mt] = *(const short8*)(As + aAddr[mt]);
    #pragma unroll
    for (int nt = 0; nt < 4; ++nt) bfr[nt] = *(const short8*)(Bs + bAddr[nt]);
    #pragma unroll
    for (int mt = 0; mt < 4; ++mt)
      #pragma unroll
      for (int nt = 0; nt < 4; ++nt)
        acc[mt][nt] = __builtin_amdgcn_mfma_f32_16x16x32_bf16(af[mt], bfr[nt], acc[mt][nt], 0, 0, 0);
  }

  // epilogue: C/D layout col=lane&15, row=(lane>>4)*4+reg
  #pragma unroll
  for (int mt = 0; mt < 4; ++mt) {
    int rbase = bm + wm * 64 + mt * 16 + ((l >> 4) << 2);
    #pragma unroll
    for (int nt = 0; nt < 4; ++nt) {
      int col = wn * 64 + nt * 16 + (l & 15);
      #pragma unroll
      for (int r = 0; r < 4; ++r) {
        int row = rbase + r;
        if (row < M) C[(size_t)row * HDIM + col] = acc[mt][nt][r];
      }
    }
  }
}

// ---------------- per-node row dots: s = xl . a_src, d = xl . a_dst ----------------

__global__ __launch_bounds__(256) void k_rowdots(const float* __restrict__ xl,
                                                 const float* __restrict__ av,
                                                 const float* __restrict__ dv,
                                                 float* __restrict__ sOut,
                                                 float* __restrict__ dOut, int n) {
  int node = blockIdx.x * 4 + (threadIdx.x >> 6);
  if (node >= n) return;
  int lane = threadIdx.x & 63;
  float4 v = *(const float4*)(xl + (size_t)node * HDIM + lane * 4);
  float4 a = *(const float4*)(av + lane * 4);
  float4 d = *(const float4*)(dv + lane * 4);
  float ps = v.x * a.x + v.y * a.y + v.z * a.z + v.w * a.w;
  float pd = v.x * d.x + v.y * d.y + v.z * d.z + v.w * d.w;
  #pragma unroll
  for (int off = 32; off; off >>= 1) {
    ps += __shfl_down(ps, off, 64);
    pd += __shfl_down(pd, off, 64);
  }
  if (lane == 0) { sOut[node] = ps; dOut[node] = pd; }
}

// ---------------- attention logits ----------------

__global__ void k_alpha_combine(const float* __restrict__ s, const float* __restrict__ d,
                                const float* __restrict__ ae, const int* __restrict__ src,
                                const int* __restrict__ dst, float* __restrict__ alpha, int E) {
  int e = blockIdx.x * 256 + threadIdx.x;
  if (e < E) {
    float a = s[src[e]] + d[dst[e]] + ae[e];
    alpha[e] = (a > 0.f) ? a : 0.2f * a;
  }
}

// ---------------- per-node softmax + aggregation (wave per node, f32 gather) ----------------

template <int OUTBF, int RELU>
__global__ __launch_bounds__(256) void k_aggregate(const float* __restrict__ xl,
                                                   const float* __restrict__ alpha,
                                                   const int* __restrict__ src,
                                                   const int* __restrict__ offsets,
                                                   const int* __restrict__ elist,
                                                   const float* __restrict__ bias,
                                                   void* __restrict__ outv, int n) {
  int node = blockIdx.x * 4 + (threadIdx.x >> 6);
  if (node >= n) return;
  int lane = threadIdx.x & 63;
  int beg = offsets[node], end = offsets[node + 1];
  float a0 = 0.f, a1 = 0.f, a2 = 0.f, a3 = 0.f;
  if (end > beg) {
    float m = -1e30f;
    for (int j = beg; j < end; ++j) m = fmaxf(m, alpha[elist[j]]);
    float den = 0.f;
    for (int j = beg; j < end; ++j) den += expf(alpha[elist[j]] - m);
    float inv = 1.f / den;
    for (int j = beg; j < end; ++j) {
      int e = elist[j];
      float wgt = expf(alpha[e] - m) * inv;
      float4 v = *(const float4*)(xl + (size_t)src[e] * HDIM + lane * 4);
      a0 += wgt * v.x;
      a1 += wgt * v.y;
      a2 += wgt * v.z;
      a3 += wgt * v.w;
    }
  }
  float4 bv = *(const float4*)(bias + lane * 4);
  float o0 = a0 + bv.x, o1 = a1 + bv.y, o2 = a2 + bv.z, o3 = a3 + bv.w;
  if (RELU) {
    o0 = fmaxf(o0, 0.f); o1 = fmaxf(o1, 0.f);
    o2 = fmaxf(o2, 0.f); o3 = fmaxf(o3, 0.f);
  }
  if (OUTBF) {
    us4 ov;
    ov[0] = f2bf(o0); ov[1] = f2bf(o1); ov[2] = f2bf(o2); ov[3] = f2bf(o3);
    *(us4*)((unsigned short*)outv + (size_t)node * HDIM + lane * 4) = ov;
  } else {
    *(float4*)((float*)outv + (size_t)node * HDIM + lane * 4) =
        make_float4(o0, o1, o2, o3);
  }
}

// ---------------- prediction head ----------------

__global__ void k_head(const float* __restrict__ titles, const int* __restrict__ nodes,
                       const float* __restrict__ Wp, const float* __restrict__ bp,
                       float* __restrict__ out, int Bn) {
  int b = blockIdx.x * 4 + (threadIdx.x >> 6);
  if (b >= Bn) return;
  int lane = threadIdx.x & 63;
  const float* r0 = titles + (size_t)nodes[b] * HDIM;
  const float* r1 = titles + (size_t)nodes[Bn + b] * HDIM;
  float s0 = 0.f, s1 = 0.f, s2 = 0.f;
  #pragma unroll
  for (int i = 0; i < 4; ++i) {
    int h = lane + 64 * i;
    float c = r0[h] * r1[h];
    s0 += c * Wp[h * 3 + 0];
    s1 += c * Wp[h * 3 + 1];
    s2 += c * Wp[h * 3 + 2];
  }
  #pragma unroll
  for (int off = 32; off; off >>= 1) {
    s0 += __shfl_down(s0, off, 64);
    s1 += __shfl_down(s1, off, 64);
    s2 += __shfl_down(s2, off, 64);
  }
  if (lane == 0) {
    out[b * 3 + 0] = s0 + bp[0];
    out[b * 3 + 1] = s1 + bp[1];
    out[b * 3 + 2] = s2 + bp[2];
  }
}

// ---------------- launch ----------------

extern "C" void kernel_launch(void* const* d_in, const int* in_sizes, int n_in,
                              void* d_out, int out_size, void* d_ws, size_t ws_size,
                              hipStream_t stream) {
  const float* x         = (const float*)d_in[0];
  const float* edge_attr = (const float*)d_in[1];
  const float* W1  = (const float*)d_in[2];
  const float* as1 = (const float*)d_in[3];
  const float* ad1 = (const float*)d_in[4];
  const float* We1 = (const float*)d_in[5];
  const float* ae1 = (const float*)d_in[6];
  const float* b1  = (const float*)d_in[7];
  const float* W2  = (const float*)d_in[8];
  const float* as2 = (const float*)d_in[9];
  const float* ad2 = (const float*)d_in[10];
  const float* We2 = (const float*)d_in[11];
  const float* ae2 = (const float*)d_in[12];
  const float* b2  = (const float*)d_in[13];
  const float* Wp  = (const float*)d_in[14];
  const float* bp  = (const float*)d_in[15];
  const int* edge_index = (const int*)d_in[16];
  const int* nodes      = (const int*)d_in[17];

  const int N  = in_sizes[0] / FDIM;
  const int E  = in_sizes[16] / 2;
  const int Bn = in_sizes[17] / 2;
  const int* srcArr = edge_index;
  const int* dstArr = edge_index + E;

  char* w = (char*)d_ws;
  auto carve = [&](size_t bytes) -> void* {
    void* p = (void*)w;
    w += (bytes + 255) & ~(size_t)255;
    return p;
  };
  float*          titles = (float*)carve(sizeof(float) * (size_t)N * HDIM);
  float*          xl     = (float*)carve(sizeof(float) * (size_t)N * HDIM);  // xl1, reused as xl2
  unsigned short* hb     = (unsigned short*)carve(2 * (size_t)N * HDIM);
  unsigned short* W1t    = (unsigned short*)carve(2 * (size_t)FDIM * HDIM);
  unsigned short* W2t    = (unsigned short*)carve(2 * (size_t)HDIM * HDIM);
  float* ae1Arr = (float*)carve(sizeof(float) * E);
  float* ae2Arr = (float*)carve(sizeof(float) * E);
  float* alphaE = (float*)carve(sizeof(float) * E);
  float* sArr = (float*)carve(sizeof(float) * N);
  float* dArr = (float*)carve(sizeof(float) * N);
  float* v1 = (float*)carve(sizeof(float) * FDIM);
  float* v2 = (float*)carve(sizeof(float) * FDIM);
  int* cnt     = (int*)carve(sizeof(int) * N);
  int* offsets = (int*)carve(sizeof(int) * (N + 1));
  int* cursor  = (int*)carve(sizeof(int) * N);
  int* elist   = (int*)carve(sizeof(int) * E);
  int* bsums   = (int*)carve(sizeof(int) * 256);

  const int nbScan = (N + 255) / 256;
  const int gGemm = (N + BM - 1) / BM;

  // CSR build (dst-indexed)
  hipMemsetAsync(cnt, 0, sizeof(int) * N, stream);
  k_hist<<<(E + 255) / 256, 256, 0, stream>>>(dstArr, cnt, E);
  k_scan1<<<nbScan, 256, 0, stream>>>(cnt, offsets, bsums, N);
  k_scan2<<<1, 256, 0, stream>>>(bsums, nbScan);
  k_scan3<<<nbScan, 256, 0, stream>>>(offsets, bsums, N);
  hipMemcpyAsync(cursor, offsets, sizeof(int) * N, hipMemcpyDeviceToDevice, stream);
  k_scatter<<<(E + 255) / 256, 256, 0, stream>>>(dstArr, cursor, elist, E);

  // edge attention terms + weight conversion
  k_compute_v<<<(2 * FDIM) / 4, 256, 0, stream>>>(We1, ae1, We2, ae2, v1, v2);
  k_edge_alpha<<<(E + 3) / 4, 256, 0, stream>>>(edge_attr, v1, v2, ae1Arr, ae2Arr, E);
  k_cvtW<<<HDIM, 256, 0, stream>>>(W1, W1t, FDIM);
  k_cvtW<<<HDIM, 256, 0, stream>>>(W2, W2t, HDIM);

  // ----- layer 1 -----
  k_gemm<true><<<gGemm, 512, 0, stream>>>(x, W1t, xl, N, FDIM);
  k_rowdots<<<(N + 3) / 4, 256, 0, stream>>>(xl, as1, ad1, sArr, dArr, N);
  k_alpha_combine<<<(E + 255) / 256, 256, 0, stream>>>(sArr, dArr, ae1Arr, srcArr, dstArr, alphaE, E);
  k_aggregate<1, 1><<<(N + 3) / 4, 256, 0, stream>>>(xl, alphaE, srcArr, offsets, elist, b1, hb, N);

  // ----- layer 2 -----
  k_gemm<false><<<gGemm, 512, 0, stream>>>(hb, W2t, xl, N, HDIM);
  k_rowdots<<<(N + 3) / 4, 256, 0, stream>>>(xl, as2, ad2, sArr, dArr, N);
  k_alpha_combine<<<(E + 255) / 256, 256, 0, stream>>>(sArr, dArr, ae2Arr, srcArr, dstArr, alphaE, E);
  k_aggregate<0, 0><<<(N + 3) / 4, 256, 0, stream>>>(xl, alphaE, srcArr, offsets, elist, b2, titles, N);

  // ----- head -----
  k_head<<<(Bn + 3) / 4, 256, 0, stream>>>(titles, nodes, Wp, bp, (float*)d_out, Bn);
}

// Round 4
// 347.409 us; speedup vs baseline: 2.1078x; 1.2283x over previous
//
#include <hip/hip_runtime.h>
#include <math.h>

#define HDIM 256
#define FDIM 768
#define BM 128
#define BK 32

typedef __attribute__((ext_vector_type(8))) short short8;
typedef __attribute__((ext_vector_type(4))) float f32x4;
typedef __attribute__((ext_vector_type(4))) unsigned short us4;

__device__ __forceinline__ unsigned short f2bf(float f) {
  unsigned int u = __float_as_uint(f);
  unsigned int r = (u + 0x7FFFu + ((u >> 16) & 1u)) >> 16;
  return (unsigned short)r;
}

__device__ __forceinline__ void gload_lds16(const void* g, void* l) {
  __builtin_amdgcn_global_load_lds(
      (const __attribute__((address_space(1))) void*)g,
      (__attribute__((address_space(3))) void*)l, 16, 0, 0);
}

// ---------------- CSR build ----------------

__global__ void k_scan1(const int* __restrict__ cnt, int* __restrict__ offsets,
                        int* __restrict__ bsums, int n) {
  __shared__ int s[256];
  int i = blockIdx.x * 256 + threadIdx.x;
  int v = (i < n) ? cnt[i] : 0;
  s[threadIdx.x] = v;
  __syncthreads();
  for (int off = 1; off < 256; off <<= 1) {
    int t = (threadIdx.x >= off) ? s[threadIdx.x - off] : 0;
    __syncthreads();
    s[threadIdx.x] += t;
    __syncthreads();
  }
  if (i < n) offsets[i + 1] = s[threadIdx.x];
  if (blockIdx.x == 0 && threadIdx.x == 0) offsets[0] = 0;
  if (threadIdx.x == 255) bsums[blockIdx.x] = s[255];
}

__global__ void k_scan2(int* __restrict__ bsums, int nb) {
  __shared__ int s[256];
  int v = (threadIdx.x < nb) ? bsums[threadIdx.x] : 0;
  s[threadIdx.x] = v;
  __syncthreads();
  for (int off = 1; off < 256; off <<= 1) {
    int t = (threadIdx.x >= off) ? s[threadIdx.x - off] : 0;
    __syncthreads();
    s[threadIdx.x] += t;
    __syncthreads();
  }
  if (threadIdx.x < nb) bsums[threadIdx.x] = s[threadIdx.x] - v;  // exclusive
}

// scan3 + cursor init (cursor[i] = offsets[i])
__global__ void k_scan3c(int* __restrict__ offsets, int* __restrict__ cursor,
                         const int* __restrict__ bsums, int n) {
  int i = blockIdx.x * 256 + threadIdx.x;
  if (i < n) {
    int v = offsets[i + 1] + bsums[blockIdx.x];
    offsets[i + 1] = v;
    if (i + 1 < n) cursor[i + 1] = v;
    if (i == 0) cursor[0] = 0;
  }
}

__global__ void k_scatter(const int* __restrict__ dst, int* __restrict__ cursor,
                          int* __restrict__ elist, int E) {
  int e = blockIdx.x * 256 + threadIdx.x;
  if (e < E) {
    int p = atomicAdd(&cursor[dst[e]], 1);
    elist[p] = e;
  }
}

// ---------------- prep: compute_v + cvtW1 + cvtW2 + hist, one dispatch ----------------

__global__ __launch_bounds__(256) void k_prep(
    const float* __restrict__ We1, const float* __restrict__ ae1,
    const float* __restrict__ We2, const float* __restrict__ ae2,
    float* __restrict__ v1, float* __restrict__ v2,
    const float* __restrict__ W1, unsigned short* __restrict__ W1t,
    const float* __restrict__ W2, unsigned short* __restrict__ W2t,
    const int* __restrict__ dstArr, int* __restrict__ cnt, int E) {
  int bid = blockIdx.x;
  if (bid < 384) {
    // v1 = We1 @ ae1, v2 = We2 @ ae2 (wave per row)
    int row = bid * 4 + (threadIdx.x >> 6);
    int lane = threadIdx.x & 63;
    const float* W = (row < FDIM) ? We1 : We2;
    const float* a = (row < FDIM) ? ae1 : ae2;
    int r = (row < FDIM) ? row : row - FDIM;
    float4 w = *(const float4*)&W[(size_t)r * HDIM + lane * 4];
    float4 av = *(const float4*)&a[lane * 4];
    float p = w.x * av.x + w.y * av.y + w.z * av.z + w.w * av.w;
    #pragma unroll
    for (int off = 32; off; off >>= 1) p += __shfl_down(p, off, 64);
    if (lane == 0) ((row < FDIM) ? v1 : v2)[r] = p;
  } else if (bid < 640) {
    int nn = bid - 384;
    for (int k = threadIdx.x; k < FDIM; k += 256)
      W1t[(size_t)nn * FDIM + k] = f2bf(W1[(size_t)k * HDIM + nn]);
  } else if (bid < 896) {
    int nn = bid - 640;
    for (int k = threadIdx.x; k < HDIM; k += 256)
      W2t[(size_t)nn * HDIM + k] = f2bf(W2[(size_t)k * HDIM + nn]);
  } else {
    int e = (bid - 896) * 256 + threadIdx.x;
    if (e < E) atomicAdd(&cnt[dstArr[e]], 1);
  }
}

// ---------------- GEMM body: C[M][HDIM](f32) = A@Bt^T, fused row-dots ----------------
// BM=128, BN=256(full), BK=32, 512 threads = 8 waves (2m x 4n), wave tile 64x64.
// LDS chunk-major: As p=c*2048+m*16 (8KB), Bs p=c*4096+n*16 (16KB), partials 4KB.

template <bool AF32>
__device__ __forceinline__ void gemm_body(unsigned char* lds,
                                          const void* __restrict__ Ain,
                                          const unsigned short* __restrict__ Bt,
                                          float* __restrict__ C,
                                          float* __restrict__ sOut,
                                          float* __restrict__ dOut,
                                          const float* __restrict__ a_src,
                                          const float* __restrict__ a_dst,
                                          int M, int K, int tile) {
  unsigned char* As = lds;
  unsigned char* Bs = lds + 8192;
  float* partS = (float*)(lds + 24576);         // [4][128]
  float* partD = (float*)(lds + 24576 + 2048);  // [4][128]
  const int t = threadIdx.x;
  const int l = t & 63;
  const int w = t >> 6;
  const int wm = w >> 2, wn = w & 3;
  const int bm = tile * BM;

  f32x4 acc[4][4] = {};

  // A staging decode (bf16 path): dest t*16 -> c = t>>7, m = t&127
  int rowA = bm + (t & 127);
  if (rowA >= M) rowA = M - 1;
  const int cA = t >> 7;
  // A reg-staging (fp32 path): m = t>>2, kb = t&3 -> p = kb*2048 + m*16
  int rowAr = bm + (t >> 2);
  if (rowAr >= M) rowAr = M - 1;
  const int kbAr = t & 3;
  const int sAr = kbAr * 2048 + (t >> 2) * 16;
  // B staging decode
  const int nB = t & 255;
  const int cB0 = t >> 8;
  const int cB1 = 2 + (t >> 8);

  int aAddr[4], bAddr[4];
  #pragma unroll
  for (int mt = 0; mt < 4; ++mt) {
    int m = wm * 64 + mt * 16 + (l & 15);
    aAddr[mt] = (l >> 4) * 2048 + m * 16;
  }
  #pragma unroll
  for (int nt = 0; nt < 4; ++nt) {
    int nn = wn * 64 + nt * 16 + (l & 15);
    bAddr[nt] = (l >> 4) * 4096 + nn * 16;
  }

  const int nsteps = K / BK;
  for (int ks = 0; ks < nsteps; ++ks) {
    const int k0 = ks * BK;
    __syncthreads();
    if (AF32) {
      const float* A = (const float*)Ain;
      const float* p = A + (size_t)rowAr * K + k0 + kbAr * 8;
      float4 f0 = *(const float4*)p;
      float4 f1 = *(const float4*)(p + 4);
      short8 hv;
      hv[0] = (short)f2bf(f0.x); hv[1] = (short)f2bf(f0.y);
      hv[2] = (short)f2bf(f0.z); hv[3] = (short)f2bf(f0.w);
      hv[4] = (short)f2bf(f1.x); hv[5] = (short)f2bf(f1.y);
      hv[6] = (short)f2bf(f1.z); hv[7] = (short)f2bf(f1.w);
      *(short8*)(As + sAr) = hv;
    } else {
      const unsigned short* A = (const unsigned short*)Ain;
      gload_lds16(A + (size_t)rowA * K + k0 + cA * 8, As + t * 16);
    }
    gload_lds16(Bt + (size_t)nB * K + k0 + cB0 * 8, Bs + t * 16);
    gload_lds16(Bt + (size_t)nB * K + k0 + cB1 * 8, Bs + 8192 + t * 16);
    __syncthreads();

    short8 af[4], bfr[4];
    #pragma unroll
    for (int mt = 0; mt < 4; ++mt) af[mt] = *(const short8*)(As + aAddr[mt]);
    #pragma unroll
    for (int nt = 0; nt < 4; ++nt) bfr[nt] = *(const short8*)(Bs + bAddr[nt]);
    #pragma unroll
    for (int mt = 0; mt < 4; ++mt)
      #pragma unroll
      for (int nt = 0; nt < 4; ++nt)
        acc[mt][nt] = __builtin_amdgcn_mfma_f32_16x16x32_bf16(af[mt], bfr[nt], acc[mt][nt], 0, 0, 0);
  }

  // epilogue: C store + fused row-dots (s = C.a_src, d = C.a_dst)
  float asv[4], adv[4];
  #pragma unroll
  for (int nt = 0; nt < 4; ++nt) {
    int col = wn * 64 + nt * 16 + (l & 15);
    asv[nt] = a_src[col];
    adv[nt] = a_dst[col];
  }
  #pragma unroll
  for (int mt = 0; mt < 4; ++mt) {
    int rloc = wm * 64 + mt * 16 + ((l >> 4) << 2);
    #pragma unroll
    for (int r = 0; r < 4; ++r) {
      int row = bm + rloc + r;
      float ps = 0.f, pd = 0.f;
      #pragma unroll
      for (int nt = 0; nt < 4; ++nt) {
        float v = acc[mt][nt][r];
        if (row < M) C[(size_t)row * HDIM + wn * 64 + nt * 16 + (l & 15)] = v;
        ps += v * asv[nt];
        pd += v * adv[nt];
      }
      #pragma unroll
      for (int off = 1; off < 16; off <<= 1) {
        ps += __shfl_xor(ps, off, 64);
        pd += __shfl_xor(pd, off, 64);
      }
      if ((l & 15) == 0) {
        partS[wn * 128 + rloc + r] = ps;
        partD[wn * 128 + rloc + r] = pd;
      }
    }
  }
  __syncthreads();
  if (t < 128) {
    int row = bm + t;
    if (row < M) {
      sOut[row] = partS[t] + partS[128 + t] + partS[256 + t] + partS[384 + t];
      dOut[row] = partD[t] + partD[128 + t] + partD[256 + t] + partD[384 + t];
    }
  }
}

// ---------------- edge-alpha body (8 edges per 512-thread block) ----------------

__device__ __forceinline__ void edge_body(unsigned char* lds,
                                          const float* __restrict__ ea,
                                          const float* __restrict__ v1,
                                          const float* __restrict__ v2,
                                          float* __restrict__ o1,
                                          float* __restrict__ o2, int E, int ebid) {
  float* sv1 = (float*)lds;
  float* sv2 = (float*)(lds + 3072);
  for (int i = threadIdx.x; i < FDIM; i += 512) { sv1[i] = v1[i]; sv2[i] = v2[i]; }
  __syncthreads();
  int e = ebid * 8 + (threadIdx.x >> 6);
  if (e >= E) return;
  int lane = threadIdx.x & 63;
  const float* row = ea + (size_t)e * FDIM;
  float p1 = 0.f, p2 = 0.f;
  #pragma unroll
  for (int t = 0; t < 3; ++t) {
    int idx = t * 256 + lane * 4;
    float4 x = *(const float4*)&row[idx];
    float4 a = *(const float4*)&sv1[idx];
    float4 b = *(const float4*)&sv2[idx];
    p1 += x.x * a.x + x.y * a.y + x.z * a.z + x.w * a.w;
    p2 += x.x * b.x + x.y * b.y + x.z * b.z + x.w * b.w;
  }
  #pragma unroll
  for (int off = 32; off; off >>= 1) {
    p1 += __shfl_down(p1, off, 64);
    p2 += __shfl_down(p2, off, 64);
  }
  if (lane == 0) { o1[e] = p1; o2[e] = p2; }
}

// ---------------- fat kernel 1: GEMM1 tiles || edge-alpha blocks ----------------

__global__ __launch_bounds__(512) void k_fat1(
    const float* __restrict__ x, const unsigned short* __restrict__ W1t,
    float* __restrict__ xl, float* __restrict__ sArr, float* __restrict__ dArr,
    const float* __restrict__ as1, const float* __restrict__ ad1, int M,
    const float* __restrict__ ea, const float* __restrict__ v1,
    const float* __restrict__ v2, float* __restrict__ ae1Arr,
    float* __restrict__ ae2Arr, int E, int nGemm) {
  __shared__ unsigned char lds[28672];
  if ((int)blockIdx.x < nGemm)
    gemm_body<true>(lds, x, W1t, xl, sArr, dArr, as1, ad1, M, FDIM, blockIdx.x);
  else
    edge_body(lds, ea, v1, v2, ae1Arr, ae2Arr, E, blockIdx.x - nGemm);
}

__global__ __launch_bounds__(512) void k_gemm2(
    const unsigned short* __restrict__ hb, const unsigned short* __restrict__ W2t,
    float* __restrict__ xl, float* __restrict__ sArr, float* __restrict__ dArr,
    const float* __restrict__ as2, const float* __restrict__ ad2, int M) {
  __shared__ unsigned char lds[28672];
  gemm_body<false>(lds, hb, W2t, xl, sArr, dArr, as2, ad2, M, HDIM, blockIdx.x);
}

// ---------------- aggregate: fused logits + online softmax + weighted gather ----------------

template <int OUTBF, int RELU>
__global__ __launch_bounds__(256) void k_aggregate(const float* __restrict__ xl,
                                                   const float* __restrict__ sArr,
                                                   const float* __restrict__ dArr,
                                                   const float* __restrict__ aeArr,
                                                   const int* __restrict__ src,
                                                   const int* __restrict__ offsets,
                                                   const int* __restrict__ elist,
                                                   const float* __restrict__ bias,
                                                   void* __restrict__ outv, int n) {
  int node = blockIdx.x * 4 + (threadIdx.x >> 6);
  if (node >= n) return;
  int lane = threadIdx.x & 63;
  int beg = offsets[node], end = offsets[node + 1];
  float dnode = dArr[node];
  float run_m = -1e30f, run_den = 0.f;
  float a0 = 0.f, a1 = 0.f, a2 = 0.f, a3 = 0.f;
  for (int c0 = beg; c0 < end; c0 += 64) {
    int j = c0 + lane;
    float al = -1e30f;
    int sj = 0;
    if (j < end) {
      int e = elist[j];
      sj = src[e];
      float a = sArr[sj] + dnode + aeArr[e];
      al = (a > 0.f) ? a : 0.2f * a;
    }
    float cm = al;
    #pragma unroll
    for (int off = 32; off; off >>= 1) cm = fmaxf(cm, __shfl_xor(cm, off, 64));
    float new_m = fmaxf(run_m, cm);
    float ev = (j < end) ? expf(al - new_m) : 0.f;
    float csum = ev;
    #pragma unroll
    for (int off = 32; off; off >>= 1) csum += __shfl_xor(csum, off, 64);
    float scale = expf(run_m - new_m);
    run_den = run_den * scale + csum;
    a0 *= scale; a1 *= scale; a2 *= scale; a3 *= scale;
    int cdeg = end - c0;
    if (cdeg > 64) cdeg = 64;
    for (int q = 0; q < cdeg; ++q) {
      float wgt = __shfl(ev, q, 64);
      int sq = __shfl(sj, q, 64);
      float4 v = *(const float4*)(xl + (size_t)sq * HDIM + lane * 4);
      a0 += wgt * v.x; a1 += wgt * v.y; a2 += wgt * v.z; a3 += wgt * v.w;
    }
    run_m = new_m;
  }
  float inv = (end > beg) ? 1.f / run_den : 0.f;
  float4 bv = *(const float4*)(bias + lane * 4);
  float o0 = a0 * inv + bv.x, o1 = a1 * inv + bv.y;
  float o2 = a2 * inv + bv.z, o3 = a3 * inv + bv.w;
  if (RELU) {
    o0 = fmaxf(o0, 0.f); o1 = fmaxf(o1, 0.f);
    o2 = fmaxf(o2, 0.f); o3 = fmaxf(o3, 0.f);
  }
  if (OUTBF) {
    us4 ov;
    ov[0] = f2bf(o0); ov[1] = f2bf(o1); ov[2] = f2bf(o2); ov[3] = f2bf(o3);
    *(us4*)((unsigned short*)outv + (size_t)node * HDIM + lane * 4) = ov;
  } else {
    *(float4*)((float*)outv + (size_t)node * HDIM + lane * 4) =
        make_float4(o0, o1, o2, o3);
  }
}

// ---------------- prediction head ----------------

__global__ void k_head(const float* __restrict__ titles, const int* __restrict__ nodes,
                       const float* __restrict__ Wp, const float* __restrict__ bp,
                       float* __restrict__ out, int Bn) {
  int b = blockIdx.x * 4 + (threadIdx.x >> 6);
  if (b >= Bn) return;
  int lane = threadIdx.x & 63;
  const float* r0 = titles + (size_t)nodes[b] * HDIM;
  const float* r1 = titles + (size_t)nodes[Bn + b] * HDIM;
  float s0 = 0.f, s1 = 0.f, s2 = 0.f;
  #pragma unroll
  for (int i = 0; i < 4; ++i) {
    int h = lane + 64 * i;
    float c = r0[h] * r1[h];
    s0 += c * Wp[h * 3 + 0];
    s1 += c * Wp[h * 3 + 1];
    s2 += c * Wp[h * 3 + 2];
  }
  #pragma unroll
  for (int off = 32; off; off >>= 1) {
    s0 += __shfl_down(s0, off, 64);
    s1 += __shfl_down(s1, off, 64);
    s2 += __shfl_down(s2, off, 64);
  }
  if (lane == 0) {
    out[b * 3 + 0] = s0 + bp[0];
    out[b * 3 + 1] = s1 + bp[1];
    out[b * 3 + 2] = s2 + bp[2];
  }
}

// ---------------- launch ----------------

extern "C" void kernel_launch(void* const* d_in, const int* in_sizes, int n_in,
                              void* d_out, int out_size, void* d_ws, size_t ws_size,
                              hipStream_t stream) {
  const float* x         = (const float*)d_in[0];
  const float* edge_attr = (const float*)d_in[1];
  const float* W1  = (const float*)d_in[2];
  const float* as1 = (const float*)d_in[3];
  const float* ad1 = (const float*)d_in[4];
  const float* We1 = (const float*)d_in[5];
  const float* ae1 = (const float*)d_in[6];
  const float* b1  = (const float*)d_in[7];
  const float* W2  = (const float*)d_in[8];
  const float* as2 = (const float*)d_in[9];
  const float* ad2 = (const float*)d_in[10];
  const float* We2 = (const float*)d_in[11];
  const float* ae2 = (const float*)d_in[12];
  const float* b2  = (const float*)d_in[13];
  const float* Wp  = (const float*)d_in[14];
  const float* bp  = (const float*)d_in[15];
  const int* edge_index = (const int*)d_in[16];
  const int* nodes      = (const int*)d_in[17];

  const int N  = in_sizes[0] / FDIM;
  const int E  = in_sizes[16] / 2;
  const int Bn = in_sizes[17] / 2;
  const int* srcArr = edge_index;
  const int* dstArr = edge_index + E;

  char* w = (char*)d_ws;
  auto carve = [&](size_t bytes) -> void* {
    void* p = (void*)w;
    w += (bytes + 255) & ~(size_t)255;
    return p;
  };
  float*          titles = (float*)carve(sizeof(float) * (size_t)N * HDIM);
  float*          xl     = (float*)carve(sizeof(float) * (size_t)N * HDIM);
  unsigned short* hb     = (unsigned short*)carve(2 * (size_t)N * HDIM);
  unsigned short* W1t    = (unsigned short*)carve(2 * (size_t)FDIM * HDIM);
  unsigned short* W2t    = (unsigned short*)carve(2 * (size_t)HDIM * HDIM);
  float* ae1Arr = (float*)carve(sizeof(float) * E);
  float* ae2Arr = (float*)carve(sizeof(float) * E);
  float* sArr = (float*)carve(sizeof(float) * N);
  float* dArr = (float*)carve(sizeof(float) * N);
  float* v1 = (float*)carve(sizeof(float) * FDIM);
  float* v2 = (float*)carve(sizeof(float) * FDIM);
  int* cnt     = (int*)carve(sizeof(int) * N);
  int* offsets = (int*)carve(sizeof(int) * (N + 1));
  int* cursor  = (int*)carve(sizeof(int) * N);
  int* elist   = (int*)carve(sizeof(int) * E);
  int* bsums   = (int*)carve(sizeof(int) * 256);

  const int nbScan = (N + 255) / 256;
  const int nbHist = (E + 255) / 256;
  const int nGemm = (N + BM - 1) / BM;
  const int nEdge = (E + 7) / 8;

  // prep (compute_v + cvtW + hist) — hist needs zeroed cnt first
  hipMemsetAsync(cnt, 0, sizeof(int) * N, stream);
  k_prep<<<896 + nbHist, 256, 0, stream>>>(We1, ae1, We2, ae2, v1, v2,
                                           W1, W1t, W2, W2t, dstArr, cnt, E);
  // CSR scan chain
  k_scan1<<<nbScan, 256, 0, stream>>>(cnt, offsets, bsums, N);
  k_scan2<<<1, 256, 0, stream>>>(bsums, nbScan);
  k_scan3c<<<nbScan, 256, 0, stream>>>(offsets, cursor, bsums, N);
  k_scatter<<<nbHist, 256, 0, stream>>>(dstArr, cursor, elist, E);

  // fat: GEMM1 (+row-dots) || edge-alpha (both layers)
  k_fat1<<<nGemm + nEdge, 512, 0, stream>>>(x, W1t, xl, sArr, dArr, as1, ad1, N,
                                            edge_attr, v1, v2, ae1Arr, ae2Arr, E, nGemm);
  // layer 1 aggregate (fused logits+softmax+gather)
  k_aggregate<1, 1><<<(N + 3) / 4, 256, 0, stream>>>(xl, sArr, dArr, ae1Arr, srcArr,
                                                     offsets, elist, b1, hb, N);
  // layer 2
  k_gemm2<<<nGemm, 512, 0, stream>>>(hb, W2t, xl, sArr, dArr, as2, ad2, N);
  k_aggregate<0, 0><<<(N + 3) / 4, 256, 0, stream>>>(xl, sArr, dArr, ae2Arr, srcArr,
                                                     offsets, elist, b2, titles, N);
  // head
  k_head<<<(Bn + 3) / 4, 256, 0, stream>>>(titles, nodes, Wp, bp, (float*)d_out, Bn);
}